// Round 3
// baseline (2396.656 us; speedup 1.0000x reference)
//
#include <hip/hip_runtime.h>

// SurfSageEncoder: 3x SAGEConv(mean) + linear head, fp32.
// N=50000 nodes, E=600000 edges, D: 128 -> 128 -> 128 -> 64 -> 64.
//
// R2 changes (profile-driven):
//  - k_linear rebuilt: global_load_lds(16B) A-staging, double-buffered LDS,
//    W reg-prefetch, Bt staging remapped (j = t%COLS, pad COLS+4) to kill the
//    8-way bank conflict (was 5.6M conflict-cycles/dispatch).
//  - k_agg unrolled x4 for memory-level parallelism.

#define BLK 256

__device__ __forceinline__ void gload_lds16(const float* gp, float* lp) {
  __builtin_amdgcn_global_load_lds(
      (const __attribute__((address_space(1))) void*)gp,
      (__attribute__((address_space(3))) void*)lp, 16, 0, 0);
}

// ---------------- CSR build ----------------

__global__ __launch_bounds__(BLK) void k_hist(const int* __restrict__ dst,
                                              int* __restrict__ deg, int E) {
  int i = blockIdx.x * BLK + threadIdx.x;
  int stride = gridDim.x * BLK;
  for (; i < E; i += stride) atomicAdd(&deg[dst[i]], 1);
}

__global__ __launch_bounds__(BLK) void k_scan1(const int* __restrict__ deg,
                                               int* __restrict__ offs,
                                               int* __restrict__ bsums, int n) {
  __shared__ int lds[BLK];
  int t = threadIdx.x;
  int base = blockIdx.x * 1024 + t * 4;
  int v0 = (base + 0 < n) ? deg[base + 0] : 0;
  int v1 = (base + 1 < n) ? deg[base + 1] : 0;
  int v2 = (base + 2 < n) ? deg[base + 2] : 0;
  int v3 = (base + 3 < n) ? deg[base + 3] : 0;
  int s = v0 + v1 + v2 + v3;
  lds[t] = s;
  __syncthreads();
  for (int off = 1; off < BLK; off <<= 1) {
    int x = 0;
    if (t >= off) x = lds[t - off];
    __syncthreads();
    if (t >= off) lds[t] += x;
    __syncthreads();
  }
  int excl = lds[t] - s;
  if (base + 0 < n) offs[base + 0] = excl;
  if (base + 1 < n) offs[base + 1] = excl + v0;
  if (base + 2 < n) offs[base + 2] = excl + v0 + v1;
  if (base + 3 < n) offs[base + 3] = excl + v0 + v1 + v2;
  if (t == BLK - 1) bsums[blockIdx.x] = lds[BLK - 1];
}

__global__ void k_scan2(int* __restrict__ bsums, int nb) {
  if (blockIdx.x == 0 && threadIdx.x == 0) {
    int acc = 0;
    for (int i = 0; i < nb; ++i) { int v = bsums[i]; bsums[i] = acc; acc += v; }
  }
}

__global__ __launch_bounds__(BLK) void k_scan3(int* __restrict__ offs,
                                               const int* __restrict__ bsums,
                                               int* __restrict__ cursor, int n, int E) {
  int i = blockIdx.x * BLK + threadIdx.x;
  if (i < n) {
    int o = offs[i] + bsums[i >> 10];
    offs[i] = o;
    cursor[i] = o;
  }
  if (i == 0) offs[n] = E;
}

__global__ __launch_bounds__(BLK) void k_fill(const int* __restrict__ src,
                                              const int* __restrict__ dst,
                                              int* __restrict__ cursor,
                                              int* __restrict__ csr, int E) {
  int i = blockIdx.x * BLK + threadIdx.x;
  int stride = gridDim.x * BLK;
  for (; i < E; i += stride) {
    int p = atomicAdd(&cursor[dst[i]], 1);
    csr[p] = src[i];
  }
}

// ---------------- mean aggregation: one wave per node, D=128 ----------------

__global__ __launch_bounds__(BLK) void k_agg(const float* __restrict__ in,
                                             const int* __restrict__ offs,
                                             const int* __restrict__ csr,
                                             float* __restrict__ outmean, int n) {
  int wid = (blockIdx.x * BLK + threadIdx.x) >> 6;
  int lane = threadIdx.x & 63;
  if (wid >= n) return;
  int beg = offs[wid], end = offs[wid + 1];
  const float2* in2 = (const float2*)in;
  float ax = 0.f, ay = 0.f;
  int e = beg;
  for (; e + 3 < end; e += 4) {  // 4 rows in flight
    int s0 = csr[e], s1 = csr[e + 1], s2 = csr[e + 2], s3 = csr[e + 3];
    float2 a = in2[s0 * 64 + lane];
    float2 b = in2[s1 * 64 + lane];
    float2 c = in2[s2 * 64 + lane];
    float2 d = in2[s3 * 64 + lane];
    ax += a.x + b.x + c.x + d.x;
    ay += a.y + b.y + c.y + d.y;
  }
  for (; e < end; ++e) {
    int s = csr[e];
    float2 a = in2[s * 64 + lane];
    ax += a.x; ay += a.y;
  }
  int d = end - beg;
  float inv = 1.0f / (float)(d > 0 ? d : 1);
  float2 r; r.x = ax * inv; r.y = ay * inv;
  ((float2*)outmean)[wid * 64 + lane] = r;
}

// 64-dim mean-agg of P (cols 0..63 of PQ) plus Q (cols 64..127).
__global__ __launch_bounds__(BLK) void k_agg_add(const float* __restrict__ PQ,
                                                 const int* __restrict__ offs,
                                                 const int* __restrict__ csr,
                                                 float* __restrict__ outv, int n) {
  int wid = (blockIdx.x * BLK + threadIdx.x) >> 6;
  int lane = threadIdx.x & 63;
  if (wid >= n) return;
  int beg = offs[wid], end = offs[wid + 1];
  float a = 0.f;
  int e = beg;
  for (; e + 3 < end; e += 4) {
    int s0 = csr[e], s1 = csr[e + 1], s2 = csr[e + 2], s3 = csr[e + 3];
    a += PQ[s0 * 128 + lane] + PQ[s1 * 128 + lane] +
         PQ[s2 * 128 + lane] + PQ[s3 * 128 + lane];
  }
  for (; e < end; ++e) a += PQ[csr[e] * 128 + lane];
  int d = end - beg;
  float inv = 1.0f / (float)(d > 0 ? d : 1);
  outv[wid * 64 + lane] = a * inv + PQ[wid * 128 + 64 + lane];
}

// ---------------- fused linear GEMM ----------------
// out[64 rows x COLS] per block. Phase 0: A0@W0^T (NS0 K-slabs of 32);
// phase 1: A1@W1^T (NS1 slabs). DUAL: single phase, cols<64 from W0 (no bias),
// cols>=64 from W1 (+bias). A staged via async global_load_lds into unpadded
// As[64][32] (reads are 2-addr broadcasts => conflict-free). W staged via regs
// into transposed Bt[32][COLS+4] with j=t%COLS mapping (2-way writes = free).
// Double-buffered LDS; next-slab loads issued before current compute.

template <int COLS, int NS0, int NS1, bool RELU, bool DUAL>
__global__ __launch_bounds__(BLK, 3) void k_linear(
    const float* __restrict__ A0, const float* __restrict__ W0,
    const float* __restrict__ A1, const float* __restrict__ W1,
    const float* __restrict__ bias, float* __restrict__ out, int M) {
  constexpr int KT = 32;
  constexpr int NSLAB = NS0 + NS1;
  constexpr int K0 = NS0 * KT;
  constexpr int K1 = NS1 * KT;
  constexpr int TC = COLS / 4;        // 32 or 16
  constexpr int TR = BLK / TC;        // 8 or 16
  constexpr int RPT = 64 / TR;        // 8 or 4
  constexpr int BTS = COLS + 4;       // 16B-aligned row stride, bank-spread
  constexpr int F = COLS / 32;        // W float4s per thread per slab (4 or 2)
  constexpr int KSPAN = KT / (BLK / COLS);  // 16 or 8

  __shared__ float As[2][64 * KT];
  __shared__ float Bt[2][KT * BTS];

  const int tid = threadIdx.x;
  const int tc = tid % TC, tr = tid / TC;
  const int j0 = tc * 4;
  const int rbase = tr * RPT;
  const int growbase = blockIdx.x * 64;

  const int bj = tid % COLS;              // staging column
  const int kqb = (tid / COLS) * KSPAN;   // staging k-base

  float4 acc[RPT];
#pragma unroll
  for (int rr = 0; rr < RPT; ++rr) acc[rr] = make_float4(0.f, 0.f, 0.f, 0.f);

  float4 wr[F];

  auto issueAs = [&](int s, int b) {
    const float* A = (s < NS0) ? A0 : A1;
    const int KA = (s < NS0) ? K0 : K1;
    const int k0 = ((s < NS0) ? s : s - NS0) * KT;
#pragma unroll
    for (int r = 0; r < 2; ++r) {
      const int i = r * BLK + tid;        // 0..511
      const int row = i >> 3, seg = i & 7;
      const int gr = growbase + row;
      if (gr < M)
        gload_lds16(&A[(size_t)gr * KA + k0 + seg * 4], &As[b][i * 4]);
    }
  };

  auto loadBt = [&](int s) {
    const int k0 = ((s < NS0) ? s : s - NS0) * KT;
    const float* Wrow;
    if (DUAL) {
      Wrow = (bj < 64) ? (W0 + (size_t)bj * K0) : (W1 + (size_t)(bj - 64) * K0);
    } else {
      Wrow = (s < NS0) ? (W0 + (size_t)bj * K0) : (W1 + (size_t)bj * K1);
    }
#pragma unroll
    for (int f = 0; f < F; ++f)
      wr[f] = *(const float4*)&Wrow[k0 + kqb + f * 4];
  };

  auto writeBt = [&](int b) {
#pragma unroll
    for (int f = 0; f < F; ++f) {
      const int kk = kqb + f * 4;
      Bt[b][(kk + 0) * BTS + bj] = wr[f].x;
      Bt[b][(kk + 1) * BTS + bj] = wr[f].y;
      Bt[b][(kk + 2) * BTS + bj] = wr[f].z;
      Bt[b][(kk + 3) * BTS + bj] = wr[f].w;
    }
  };

  auto compute = [&](int b) {
#pragma unroll
    for (int kk = 0; kk < KT; kk += 4) {
      float4 a4[RPT];
#pragma unroll
      for (int rr = 0; rr < RPT; ++rr)
        a4[rr] = *(const float4*)&As[b][(rbase + rr) * KT + kk];
#pragma unroll
      for (int dk = 0; dk < 4; ++dk) {
        const float4 bv = *(const float4*)&Bt[b][(kk + dk) * BTS + j0];
#pragma unroll
        for (int rr = 0; rr < RPT; ++rr) {
          const float av = (dk == 0) ? a4[rr].x : (dk == 1) ? a4[rr].y
                         : (dk == 2) ? a4[rr].z : a4[rr].w;
          acc[rr].x += av * bv.x;
          acc[rr].y += av * bv.y;
          acc[rr].z += av * bv.z;
          acc[rr].w += av * bv.w;
        }
      }
    }
  };

  int buf = 0;
  issueAs(0, 0);
  loadBt(0);
  writeBt(0);
  __syncthreads();

  for (int s = 0; s < NSLAB; ++s) {
    if (s + 1 < NSLAB) {
      issueAs(s + 1, buf ^ 1);   // async DMA, drains at the barrier
      loadBt(s + 1);             // W regs in flight under compute
    }
    compute(buf);
    if (s + 1 < NSLAB) writeBt(buf ^ 1);  // other buffer: no extra barrier
    __syncthreads();
    buf ^= 1;
  }

  float4 bv4 = make_float4(0.f, 0.f, 0.f, 0.f);
  if (!DUAL) {
    bv4 = *(const float4*)&bias[j0];
  } else if (j0 >= 64) {
    bv4 = *(const float4*)&bias[j0 - 64];
  }
#pragma unroll
  for (int rr = 0; rr < RPT; ++rr) {
    const int gr = growbase + rbase + rr;
    if (gr < M) {
      float4 o = acc[rr];
      o.x += bv4.x; o.y += bv4.y; o.z += bv4.z; o.w += bv4.w;
      if (RELU) {
        o.x = fmaxf(o.x, 0.f); o.y = fmaxf(o.y, 0.f);
        o.z = fmaxf(o.z, 0.f); o.w = fmaxf(o.w, 0.f);
      }
      *(float4*)&out[(size_t)gr * COLS + j0] = o;
    }
  }
}

// ---------------- launch ----------------

extern "C" void kernel_launch(void* const* d_in, const int* in_sizes, int n_in,
                              void* d_out, int out_size, void* d_ws, size_t ws_size,
                              hipStream_t stream) {
  const float* x    = (const float*)d_in[0];
  const int*   edge = (const int*)d_in[1];
  const float* Wl1  = (const float*)d_in[2];
  const float* bl1  = (const float*)d_in[3];
  const float* Wr1  = (const float*)d_in[4];
  const float* Wl2  = (const float*)d_in[5];
  const float* bl2  = (const float*)d_in[6];
  const float* Wr2  = (const float*)d_in[7];
  const float* Wl3  = (const float*)d_in[8];
  const float* bl3  = (const float*)d_in[9];
  const float* Wr3  = (const float*)d_in[10];
  const float* Wreg = (const float*)d_in[11];
  const float* breg = (const float*)d_in[12];

  const int N = in_sizes[0] / 128;  // 50000
  const int E = in_sizes[1] / 2;    // 600000
  const int* src = edge;
  const int* dst = edge + E;

  char* ws = (char*)d_ws;
  size_t off = 0;
  auto alloc = [&](size_t bytes) {
    void* p = ws + off;
    off = (off + bytes + 255) & ~(size_t)255;
    return p;
  };
  int*   deg    = (int*)alloc((size_t)N * 4);
  int*   offs   = (int*)alloc((size_t)(N + 1) * 4);
  int*   cursor = (int*)alloc((size_t)N * 4);
  int*   csr    = (int*)alloc((size_t)E * 4);
  int*   bsums  = (int*)alloc(256 * 4);
  float* mean   = (float*)alloc((size_t)N * 128 * 4);  // also PQ buffer (layer 3)
  float* hA     = (float*)alloc((size_t)N * 128 * 4);
  float* hB     = (float*)alloc((size_t)N * 128 * 4);
  (void)ws_size;

  // --- CSR build ---
  hipMemsetAsync(deg, 0, (size_t)N * 4, stream);
  k_hist<<<2048, BLK, 0, stream>>>(dst, deg, E);
  int nb = (N + 1023) >> 10;
  k_scan1<<<nb, BLK, 0, stream>>>(deg, offs, bsums, N);
  k_scan2<<<1, 64, 0, stream>>>(bsums, nb);
  k_scan3<<<(N + BLK - 1) / BLK, BLK, 0, stream>>>(offs, bsums, cursor, N, E);
  k_fill<<<2048, BLK, 0, stream>>>(src, dst, cursor, csr, E);

  const int aggGrid = (N * 64 + BLK - 1) / BLK;
  const int gemmGrid = (N + 63) / 64;

  // --- layer 1: h1 = relu(mean(x)@Wl1^T + x@Wr1^T + bl1) ---
  k_agg<<<aggGrid, BLK, 0, stream>>>(x, offs, csr, mean, N);
  k_linear<128, 4, 4, true, false><<<gemmGrid, BLK, 0, stream>>>(
      mean, Wl1, x, Wr1, bl1, hA, N);

  // --- layer 2 ---
  k_agg<<<aggGrid, BLK, 0, stream>>>(hA, offs, csr, mean, N);
  k_linear<128, 4, 4, true, false><<<gemmGrid, BLK, 0, stream>>>(
      mean, Wl2, hA, Wr2, bl2, hB, N);

  // --- layer 3 (transform-before-aggregate): PQ = [hB@Wl3^T | hB@Wr3^T+bl3] ---
  k_linear<128, 4, 0, false, true><<<gemmGrid, BLK, 0, stream>>>(
      hB, Wl3, (const float*)nullptr, Wr3, bl3, mean, N);
  k_agg_add<<<aggGrid, BLK, 0, stream>>>(mean, offs, csr, hA, N);

  // --- head: out = h3@Wreg^T + breg ---
  k_linear<64, 2, 0, false, false><<<gemmGrid, BLK, 0, stream>>>(
      hA, Wreg, (const float*)nullptr, (const float*)nullptr, breg,
      (float*)d_out, N);
}